// Round 2
// baseline (339.893 us; speedup 1.0000x reference)
//
#include <hip/hip_runtime.h>

// D = 16777216 elements, fp32. Inputs: x, l_in, u_in (each D).
// Outputs concatenated: [spu(x) | l_out | u_out], 3*D floats.
// Pure elementwise -> memory-bound. 24 B/elem traffic, ~64 us roofline.

__device__ __forceinline__ float sig_negt(float t) {
    // sigmoid(-t) = 1 / (1 + e^t). For large positive t, __expf -> inf -> 0. No NaN.
    return 1.0f / (1.0f + __expf(t));
}

__device__ __forceinline__ float spu_f(float t) {
    // x^2 - 0.5 for t >= 0, sigmoid(-t) - 1 for t < 0
    float s = sig_negt(t);
    return (t >= 0.0f) ? (t * t - 0.5f) : (s - 1.0f);
}

__device__ __forceinline__ float dx_spu_f(float t) {
    float s = sig_negt(t);
    return (t >= 0.0f) ? (2.0f * t) : (-s * (1.0f - s));
}

__device__ __forceinline__ void spu_elem(float x, float l, float u,
                                         float& x_out, float& l_out, float& u_out) {
    x_out = spu_f(x);

    // p = clip(x, l, u)
    float p = fminf(fmaxf(x, l), u);

    float spu_l = spu_f(l);
    float spu_u = spu_f(u);
    float spu_p = spu_f(p);

    // chord through (l, spu_l) and (u, spu_u); u - l >= 2e-3 guaranteed
    float chord_slope = (spu_u - spu_l) / (u - l);
    float chord_int   = spu_l - chord_slope * l;

    // tangent at p
    float tan_slope = dx_spu_f(p);
    float tan_int   = spu_p - p * tan_slope;

    // line through (l, spu_l) and (0, -0.5)
    float safe_l   = (l != 0.0f) ? l : 1.0f;
    float l0_slope = (-0.5f - spu_l) / (0.0f - safe_l);
    float l0_int   = -0.5f;

    bool u_pos    = (u > 0.0f);
    bool p_nonneg = (p >= 0.0f);

    float lb_slope = u_pos ? (p_nonneg ? tan_slope : l0_slope) : chord_slope;
    float lb_int   = u_pos ? (p_nonneg ? tan_int   : l0_int)   : chord_int;
    float ub_slope = u_pos ? chord_slope : tan_slope;
    float ub_int   = u_pos ? chord_int   : tan_int;

    // faithful reproduction of the reference output formulas
    l_out = lb_int + ((lb_slope > 0.0f) ? (l * (-lb_slope)) : (u * lb_slope));
    u_out = ub_int + ((ub_slope > 0.0f) ? (u * ub_slope)    : (l * (-lb_slope)));
}

__global__ void __launch_bounds__(256)
spu_transformer_kernel(const float4* __restrict__ x,
                       const float4* __restrict__ l,
                       const float4* __restrict__ u,
                       float4* __restrict__ out_x,
                       float4* __restrict__ out_l,
                       float4* __restrict__ out_u,
                       int n4) {
    int stride = gridDim.x * blockDim.x;
    for (int i = blockIdx.x * blockDim.x + threadIdx.x; i < n4; i += stride) {
        float4 xv = x[i];
        float4 lv = l[i];
        float4 uv = u[i];
        float4 ox, ol, ou;
        spu_elem(xv.x, lv.x, uv.x, ox.x, ol.x, ou.x);
        spu_elem(xv.y, lv.y, uv.y, ox.y, ol.y, ou.y);
        spu_elem(xv.z, lv.z, uv.z, ox.z, ol.z, ou.z);
        spu_elem(xv.w, lv.w, uv.w, ox.w, ol.w, ou.w);
        out_x[i] = ox;
        out_l[i] = ol;
        out_u[i] = ou;
    }
}

extern "C" void kernel_launch(void* const* d_in, const int* in_sizes, int n_in,
                              void* d_out, int out_size, void* d_ws, size_t ws_size,
                              hipStream_t stream) {
    const float* x = (const float*)d_in[0];
    const float* l = (const float*)d_in[1];
    const float* u = (const float*)d_in[2];
    float* out = (float*)d_out;

    const int D  = in_sizes[0];      // 16777216
    const int n4 = D / 4;            // divisible by 4

    float* out_x = out;
    float* out_l = out + D;
    float* out_u = out + 2 * (size_t)D;

    const int block = 256;
    int grid = 2048;                 // grid-stride; ~8 blocks/CU
    int max_grid = (n4 + block - 1) / block;
    if (grid > max_grid) grid = max_grid;

    spu_transformer_kernel<<<grid, block, 0, stream>>>(
        (const float4*)x, (const float4*)l, (const float4*)u,
        (float4*)out_x, (float4*)out_l, (float4*)out_u, n4);
}

// Round 6
// 318.952 us; speedup vs baseline: 1.0657x; 1.0657x over previous
//
#include <hip/hip_runtime.h>

// D = 16777216 elements, fp32. Inputs: x, l_in, u_in (each D).
// Outputs concatenated: [spu(x) | l_out | u_out], 3*D floats.
// Pure elementwise, zero reuse -> memory-bound. 402 MB traffic, ~62 us roofline.
// Nontemporal 16B loads/stores (native ext_vector_type), flat indexing,
// v_rcp_f32 for all divides. Scalar locals for per-lane math (ext-vector
// elements can't bind to non-const references).

typedef float float4n __attribute__((ext_vector_type(4)));

__device__ __forceinline__ float fast_rcp(float a) {
    return __builtin_amdgcn_rcpf(a);   // v_rcp_f32, ~1 ulp — fine vs 1.47 threshold
}

__device__ __forceinline__ float sig_negt(float t) {
    // sigmoid(-t) = 1 / (1 + e^t). Large t: __expf -> inf -> rcp -> 0. No NaN.
    return fast_rcp(1.0f + __expf(t));
}

__device__ __forceinline__ float spu_f(float t) {
    float s = sig_negt(t);
    return (t >= 0.0f) ? (t * t - 0.5f) : (s - 1.0f);
}

__device__ __forceinline__ float dx_spu_f(float t) {
    float s = sig_negt(t);
    return (t >= 0.0f) ? (2.0f * t) : (-s * (1.0f - s));
}

__device__ __forceinline__ void spu_elem(float x, float l, float u,
                                         float& x_out, float& l_out, float& u_out) {
    x_out = spu_f(x);

    // p = clip(x, l, u)
    float p = fminf(fmaxf(x, l), u);

    float spu_l = spu_f(l);
    float spu_u = spu_f(u);
    float spu_p = spu_f(p);

    // chord through (l, spu_l) and (u, spu_u); u - l >= 2e-3 guaranteed
    float chord_slope = (spu_u - spu_l) * fast_rcp(u - l);
    float chord_int   = spu_l - chord_slope * l;

    // tangent at p
    float tan_slope = dx_spu_f(p);
    float tan_int   = spu_p - p * tan_slope;

    // line through (l, spu_l) and (0, -0.5)
    float safe_l   = (l != 0.0f) ? l : 1.0f;
    float l0_slope = (-0.5f - spu_l) * fast_rcp(-safe_l);
    float l0_int   = -0.5f;

    bool u_pos    = (u > 0.0f);
    bool p_nonneg = (p >= 0.0f);

    float lb_slope = u_pos ? (p_nonneg ? tan_slope : l0_slope) : chord_slope;
    float lb_int   = u_pos ? (p_nonneg ? tan_int   : l0_int)   : chord_int;
    float ub_slope = u_pos ? chord_slope : tan_slope;
    float ub_int   = u_pos ? chord_int   : tan_int;

    // faithful reproduction of the reference output formulas
    l_out = lb_int + ((lb_slope > 0.0f) ? (l * (-lb_slope)) : (u * lb_slope));
    u_out = ub_int + ((ub_slope > 0.0f) ? (u * ub_slope)    : (l * (-lb_slope)));
}

__global__ void __launch_bounds__(256)
spu_transformer_kernel(const float4n* __restrict__ x,
                       const float4n* __restrict__ l,
                       const float4n* __restrict__ u,
                       float4n* __restrict__ out_x,
                       float4n* __restrict__ out_l,
                       float4n* __restrict__ out_u,
                       int n4) {
    int i = blockIdx.x * blockDim.x + threadIdx.x;
    if (i >= n4) return;

    float4n xv = __builtin_nontemporal_load(&x[i]);
    float4n lv = __builtin_nontemporal_load(&l[i]);
    float4n uv = __builtin_nontemporal_load(&u[i]);

    float oxa[4], ola[4], oua[4];
    spu_elem(xv.x, lv.x, uv.x, oxa[0], ola[0], oua[0]);
    spu_elem(xv.y, lv.y, uv.y, oxa[1], ola[1], oua[1]);
    spu_elem(xv.z, lv.z, uv.z, oxa[2], ola[2], oua[2]);
    spu_elem(xv.w, lv.w, uv.w, oxa[3], ola[3], oua[3]);

    float4n ox, ol, ou;
    ox.x = oxa[0]; ox.y = oxa[1]; ox.z = oxa[2]; ox.w = oxa[3];
    ol.x = ola[0]; ol.y = ola[1]; ol.z = ola[2]; ol.w = ola[3];
    ou.x = oua[0]; ou.y = oua[1]; ou.z = oua[2]; ou.w = oua[3];

    __builtin_nontemporal_store(ox, &out_x[i]);
    __builtin_nontemporal_store(ol, &out_l[i]);
    __builtin_nontemporal_store(ou, &out_u[i]);
}

extern "C" void kernel_launch(void* const* d_in, const int* in_sizes, int n_in,
                              void* d_out, int out_size, void* d_ws, size_t ws_size,
                              hipStream_t stream) {
    const float* x = (const float*)d_in[0];
    const float* l = (const float*)d_in[1];
    const float* u = (const float*)d_in[2];
    float* out = (float*)d_out;

    const int D  = in_sizes[0];      // 16777216
    const int n4 = D / 4;            // 4194304, divisible by 256

    float* out_x = out;
    float* out_l = out + (size_t)D;
    float* out_u = out + 2 * (size_t)D;

    const int block = 256;
    const int grid  = (n4 + block - 1) / block;   // 16384 blocks, one float4/thread

    spu_transformer_kernel<<<grid, block, 0, stream>>>(
        (const float4n*)x, (const float4n*)l, (const float4n*)u,
        (float4n*)out_x, (float4n*)out_l, (float4n*)out_u, n4);
}